// Round 7
// baseline (410.322 us; speedup 1.0000x reference)
//
#include <hip/hip_runtime.h>
#include <math.h>

#define FF 128     // feature width (all layers)
#define G0F 1024   // gemm0 blocks inside fused2 (4/CU tail)
#define GG 2048    // mfma_gemm grid

typedef _Float16 half2v __attribute__((ext_vector_type(2)));
typedef _Float16 f16x8  __attribute__((ext_vector_type(8)));
typedef __fp16   fp16x2 __attribute__((ext_vector_type(2)));
typedef __attribute__((ext_vector_type(4))) float f4v;

__device__ __forceinline__ half2v u2h(unsigned u) {
    union { unsigned u; half2v h; } c; c.u = u; return c.h;
}
__device__ __forceinline__ unsigned h2u(half2v h) {
    union { unsigned u; half2v h; } c; c.h = h; return c.u;
}
__device__ __forceinline__ unsigned short f2h(float f) {
    _Float16 h = (_Float16)f;
    unsigned short u; __builtin_memcpy(&u, &h, 2); return u;
}
__device__ __forceinline__ half2v pk2h(float e) {
    union { fp16x2 p; half2v h; } c;
    c.p = __builtin_amdgcn_cvt_pkrtz(e, e);
    return c.h;
}
__device__ __forceinline__ float dot2(half2v a, half2v b, float c) {
#if __has_builtin(__builtin_amdgcn_fdot2)
    union { half2v h; fp16x2 p; } ca, cb;
    ca.h = a; cb.h = b;
    return __builtin_amdgcn_fdot2(ca.p, cb.p, c, false);
#else
    return c + (float)a.x * (float)b.x + (float)a.y * (float)b.y;
#endif
}
__device__ __forceinline__ half2v shfladd_h(half2v v, int mask) {
    return v + u2h(__shfl_xor(h2u(v), mask));
}
// 16B-chunk XOR swizzle inside a [16 rows][256B] LDS tile.
__device__ __forceinline__ int swz16(int row, int chunk) {
    return row * 256 + (((chunk ^ row) & 15) << 4);
}

// =====================================================================
// R20: aggregate restructured to ALL-4-relation concurrent load issue.
// R19 post-mortem: fused2 overlap worked (86us vs 64+45 serial); the
// remaining >50% of runtime is 3x aggregate (~65-70us each by
// subtraction, counters never captured). Pair structure (R13) issues
// pair(2,3) gathers only after pair(0,1)'s den-reduce -- two ~500cy
// dependent-load stalls per node. Now: all 16 feature loads (fd, att,
// slot0/slot1 gathers x 4 relations) issue before ANY consumption;
// per-relation consumption reuses one acc block. 2x gather MLP.
// (The 41ms mfma_gemm row in R19's counters is a rocprof replay
// artifact: 3.4GB/s = idle wait; wall total was 374us.)
// =====================================================================

// ---------------- pack0: pack W0 + att (tiny pre-kernel) -------------
__global__ __launch_bounds__(256) void pack0(
    const float* __restrict__ W0s_, const float* __restrict__ W0d_,
    unsigned short* __restrict__ Wp,
    const float* __restrict__ a0, const float* __restrict__ a1,
    const float* __restrict__ a2, unsigned* __restrict__ attH)
{
    int b = blockIdx.x;
    const int tid = threadIdx.x;
    if (b < 512) {                       // 4r x 2mat x 128 x 128 = 131072
        const int t = b * 256 + tid;
        const int r   = t >> 15;
        const int mat = (t >> 14) & 1;
        const int idx = t & 16383;
        const int k = idx >> 7, nn = idx & 127;
        const float* W = mat ? W0d_ : W0s_;
        const float v = W[((size_t)r * FF + k) * FF + nn];
        const int nb = nn >> 4, lo = nn & 15;
        const int ks = k >> 5, quad = (k >> 3) & 3, j = k & 7;
        const int lane = quad * 16 + lo;
        const size_t o = ((((((size_t)r * 2 + mat) * 8 + nb) * 4 + ks) * 64 + lane) * 8) + j;
        Wp[o] = f2h(v);
        return;
    }
    b -= 512;
    const int t = b * 256 + tid;
    if (t >= 768) return;
    const int l = t >> 8, rest = t & 255;
    const float* a = (l == 0) ? a0 : (l == 1) ? a1 : a2;
    const float2 v = ((const float2*)a)[rest];
    half2v h = {(_Float16)v.x, (_Float16)v.y};
    attH[t] = h2u(h);
}

// ------- fused2: csr fill (record) + gemm0 + pack W1/W2 --------------
__global__ __launch_bounds__(256, 4) void fused2(
    const int* __restrict__ esrc_all, const int* __restrict__ edst_all,
    int* __restrict__ rec, int* __restrict__ ovf,
    int totalE, int ne, int n, int CB,
    const float* __restrict__ x,
    const unsigned short* __restrict__ Wp,
    const float* __restrict__ bs0, const float* __restrict__ bd0,
    unsigned short* __restrict__ fs_all, unsigned short* __restrict__ fd_all,
    int nrb,
    const float* __restrict__ W1s_, const float* __restrict__ W1d_,
    const float* __restrict__ W2s_, const float* __restrict__ W2d_,
    unsigned short* __restrict__ Wp_full)
{
    __shared__ char lsA[4096];
    __shared__ char lsC[8192];

    int b = blockIdx.x;
    const int tid = threadIdx.x;
    const int L = n << 2;

    if (b < CB) {
        // ---- padded-CSR fill, record layout, 4 chains/thread ----
        const int t0 = b * 1024 + tid;
        #pragma unroll
        for (int k = 0; k < 4; ++k) {
            const int i = t0 + k * 256;
            if (i < totalE) {
                const int r = i / ne;
                const int rd = r * n + edst_all[i];
                const int src = esrc_all[i];
                const int idx = atomicAdd(&rec[(size_t)rd * 16], 1);
                if (idx < 15)      rec[(size_t)rd * 16 + 1 + idx] = src;
                else if (idx < 32) ovf[(size_t)(idx - 15) * L + rd] = src;
            }
        }
        return;
    }
    b -= CB;

    if (b < G0F) {
        // ---- layer-0 GEMM (f32 x, packed-Wp B), LDS-staged ----
        const int wave = tid >> 6, lane = tid & 63;
        const int r = b & 3;
        const int half = wave & 1;
        const int mat  = wave >> 1;
        const int lo = lane & 15, quad = lane >> 4;

        const unsigned short* Wr = Wp + (size_t)r * 2 * FF * FF;
        const float* bp = mat ? bd0 : bs0;
        unsigned short* fs = fs_all + (size_t)r * n * FF;
        unsigned short* fd = fd_all + (size_t)r * n * FF;

        f16x8 B[4][4];
        #pragma unroll
        for (int nbi = 0; nbi < 4; ++nbi)
            #pragma unroll
            for (int ks = 0; ks < 4; ++ks) {
                const int nb = half * 4 + nbi;
                B[nbi][ks] = *(const f16x8*)
                    &Wr[(((((size_t)mat * 8 + nb) * 4 + ks) * 64 + lane) * 8)];
            }

        float bias[4];
        #pragma unroll
        for (int nbi = 0; nbi < 4; ++nbi)
            bias[nbi] = bp[r * FF + (half * 4 + nbi) * 16 + lo];

        const int srow = tid >> 4, schunk = tid & 15;
        const int stride = G0F >> 2;
        for (int rb = b >> 2; rb < nrb; rb += stride) {
            const int row0 = rb * 16;
            {
                const float* xs = &x[(size_t)row0 * FF + tid * 8];
                const float4 p0 = *(const float4*)&xs[0];
                const float4 p1 = *(const float4*)&xs[4];
                f16x8 v;
                v[0] = (_Float16)p0.x; v[1] = (_Float16)p0.y;
                v[2] = (_Float16)p0.z; v[3] = (_Float16)p0.w;
                v[4] = (_Float16)p1.x; v[5] = (_Float16)p1.y;
                v[6] = (_Float16)p1.z; v[7] = (_Float16)p1.w;
                *(f16x8*)&lsA[swz16(srow, schunk)] = v;
            }
            __syncthreads();

            f16x8 A[4];
            #pragma unroll
            for (int ks = 0; ks < 4; ++ks)
                A[ks] = *(const f16x8*)&lsA[swz16(lo, ks * 4 + quad)];

            f4v c[4];
            #pragma unroll
            for (int nbi = 0; nbi < 4; ++nbi)
                c[nbi] = (f4v){bias[nbi], bias[nbi], bias[nbi], bias[nbi]};

            #pragma unroll
            for (int ks = 0; ks < 4; ++ks)
                #pragma unroll
                for (int nbi = 0; nbi < 4; ++nbi)
                    c[nbi] = __builtin_amdgcn_mfma_f32_16x16x32_f16(
                        A[ks], B[nbi][ks], c[nbi], 0, 0, 0);

            #pragma unroll
            for (int nbi = 0; nbi < 4; ++nbi)
                #pragma unroll
                for (int i = 0; i < 4; ++i) {
                    const int row = quad * 4 + i;
                    const int cb  = ((half * 4 + nbi) * 16 + lo) * 2;
                    *(unsigned short*)&lsC[mat * 4096 + swz16(row, cb >> 4) + (cb & 15)]
                        = f2h(c[nbi][i]);
                }
            __syncthreads();

            #pragma unroll
            for (int p = 0; p < 2; ++p) {
                const int unit = p * 256 + tid;
                const int m    = unit >> 8;
                const int row  = (unit >> 4) & 15;
                const int ch   = unit & 15;
                const uint4 d = *(const uint4*)&lsC[m * 4096 + swz16(row, ch)];
                unsigned short* out = m ? fd : fs;
                *(uint4*)&out[(size_t)(row0 + row) * FF + ch * 8] = d;
            }
            __syncthreads();
        }
        return;
    }
    b -= G0F;

    // ---- pack W for layers 1,2 ----
    const int t = b * 256 + tid;
    if (t >= 2 * 4 * 2 * FF * FF) return;
    const int l    = 1 + (t >> 17);
    const int rest = t & 131071;
    const int r    = rest >> 15;
    const int mat  = (rest >> 14) & 1;
    const int idx  = rest & 16383;
    const int k = idx >> 7, nn = idx & 127;
    const float* W = (l == 1) ? (mat ? W1d_ : W1s_)
                              : (mat ? W2d_ : W2s_);
    const float v = W[((size_t)r * FF + k) * FF + nn];
    const int nb = nn >> 4, lo = nn & 15;
    const int ks = k >> 5, quad = (k >> 3) & 3, j = k & 7;
    const int lane = quad * 16 + lo;
    const size_t o = (((((((size_t)l * 4 + r) * 2 + mat) * 8 + nb) * 4 + ks) * 64 + lane) * 8) + j;
    Wp_full[o] = f2h(v);
}

// =====================================================================
// Batched MFMA GEMM over all 4 relations, f16 inputs (layers 1,2).
// =====================================================================
__global__ __launch_bounds__(256, 4) void mfma_gemm(
    const unsigned short* __restrict__ hb,
    const unsigned short* __restrict__ Wp,
    const float* __restrict__ bs_all,
    const float* __restrict__ bd_all,
    unsigned short* __restrict__ fs_all,
    unsigned short* __restrict__ fd_all,
    int nrb, int n)
{
    __shared__ char lsA[4096];
    __shared__ char lsC[8192];

    const int tid = threadIdx.x;
    const int wave = tid >> 6, lane = tid & 63;
    const int r = blockIdx.x & 3;
    const int half = wave & 1;
    const int mat  = wave >> 1;
    const int lo = lane & 15, quad = lane >> 4;

    const unsigned short* Wr = Wp + (size_t)r * 2 * FF * FF;
    const float* bp = mat ? bd_all : bs_all;
    unsigned short* fs = fs_all + (size_t)r * n * FF;
    unsigned short* fd = fd_all + (size_t)r * n * FF;

    f16x8 B[4][4];
    #pragma unroll
    for (int nbi = 0; nbi < 4; ++nbi)
        #pragma unroll
        for (int ks = 0; ks < 4; ++ks) {
            const int nb = half * 4 + nbi;
            B[nbi][ks] = *(const f16x8*)
                &Wr[(((((size_t)mat * 8 + nb) * 4 + ks) * 64 + lane) * 8)];
        }

    float bias[4];
    #pragma unroll
    for (int nbi = 0; nbi < 4; ++nbi)
        bias[nbi] = bp[r * FF + (half * 4 + nbi) * 16 + lo];

    const int srow = tid >> 4, schunk = tid & 15;
    const int stride = gridDim.x >> 2;
    for (int rb = blockIdx.x >> 2; rb < nrb; rb += stride) {
        const int row0 = rb * 16;
        {
            const uint4 g = *(const uint4*)&hb[(size_t)row0 * FF + tid * 8];
            *(uint4*)&lsA[swz16(srow, schunk)] = g;
        }
        __syncthreads();

        f16x8 A[4];
        #pragma unroll
        for (int ks = 0; ks < 4; ++ks)
            A[ks] = *(const f16x8*)&lsA[swz16(lo, ks * 4 + quad)];

        f4v c[4];
        #pragma unroll
        for (int nbi = 0; nbi < 4; ++nbi)
            c[nbi] = (f4v){bias[nbi], bias[nbi], bias[nbi], bias[nbi]};

        #pragma unroll
        for (int ks = 0; ks < 4; ++ks)
            #pragma unroll
            for (int nbi = 0; nbi < 4; ++nbi)
                c[nbi] = __builtin_amdgcn_mfma_f32_16x16x32_f16(
                    A[ks], B[nbi][ks], c[nbi], 0, 0, 0);

        #pragma unroll
        for (int nbi = 0; nbi < 4; ++nbi)
            #pragma unroll
            for (int i = 0; i < 4; ++i) {
                const int row = quad * 4 + i;
                const int cb  = ((half * 4 + nbi) * 16 + lo) * 2;
                *(unsigned short*)&lsC[mat * 4096 + swz16(row, cb >> 4) + (cb & 15)]
                    = f2h(c[nbi][i]);
            }
        __syncthreads();

        #pragma unroll
        for (int p = 0; p < 2; ++p) {
            const int unit = p * 256 + tid;
            const int m    = unit >> 8;
            const int row  = (unit >> 4) & 15;
            const int ch   = unit & 15;
            const uint4 d = *(const uint4*)&lsC[m * 4096 + swz16(row, ch)];
            unsigned short* out = m ? fd : fs;
            *(uint4*)&out[(size_t)(row0 + row) * FF + ch * 8] = d;
        }
        __syncthreads();
    }
}

// =====================================================================
// Fused aggregate. R20: ALL 4 relations' feature loads (fd, att,
// slot0+slot1 gathers) issue before any consumption; per-relation
// consumption reuses one acc block. rec gives cnt+slots in one line.
// =====================================================================
__device__ __forceinline__ void edge4(
    uint4 g, bool ok, const half2v* fdv, const half2v* atv,
    float& den, half2v* acc)
{
    const half2v C02 = {(_Float16)0.2f, (_Float16)0.2f};
    half2v f[4] = {u2h(g.x), u2h(g.y), u2h(g.z), u2h(g.w)};
    float v = 0.f;
    #pragma unroll
    for (int i = 0; i < 4; ++i) {
        const half2v z = f[i] + fdv[i];
        const half2v l = __builtin_elementwise_max(z, z * C02);
        v = dot2(l, atv[i], v);
    }
    v += __shfl_xor(v, 2);
    v += __shfl_xor(v, 1);
    const float e = ok ? __expf(v) : 0.f;
    den += e;
    const half2v eh = pk2h(e);
    #pragma unroll
    for (int i = 0; i < 4; ++i) acc[i] += eh * f[i];
}

__global__ __launch_bounds__(256) void aggregate(
    const int* __restrict__ rec,             // [R*n][16] {cnt, s0..s14}
    const int* __restrict__ ovf,             // [17][R*n] planes, idx 15..31
    const unsigned* __restrict__ fs_all,     // [R][n][64] f16 pairs
    const unsigned* __restrict__ fd_all,
    const unsigned* __restrict__ att_h,      // this layer: [R][64] f16 pairs
    unsigned* __restrict__ out_h,            // [n][64] or null
    float* __restrict__ out_f32,             // [n][32] or null
    int n)
{
    const int node = blockIdx.x * 4 + (threadIdx.x >> 6);
    if (node >= n) return;
    const int lane = threadIdx.x & 63;
    const int quarter = lane >> 4;
    const int q = lane & 15;
    const int fo = 4 * q;
    const int L = n << 2;

    // ---- metadata for all 4 relations (one 64B line each) ----
    int m[4], i0[4], i1[4];
    #pragma unroll
    for (int r = 0; r < 4; ++r) {
        const int rd = r * n + node;
        const int* rp = &rec[(size_t)rd * 16];
        m[r]  = rp[0];
        i0[r] = rp[1 + quarter];
        i1[r] = rp[5 + quarter];
    }

    // ---- issue ALL feature loads before any consumption ----
    uint4 ufd[4], uat[4], g0[4], g1[4];
    #pragma unroll
    for (int r = 0; r < 4; ++r) {
        const int rd = r * n + node;
        const unsigned* fsu = fs_all + (size_t)r * n * 64;
        ufd[r] = *(const uint4*)&fd_all[(size_t)rd * 64 + fo];
        uat[r] = *(const uint4*)&att_h[r * 64 + fo];
        const int s0 = (quarter < m[r])     ? i0[r] : 0;
        const int s1 = (4 + quarter < m[r]) ? i1[r] : 0;
        g0[r] = *(const uint4*)&fsu[(size_t)s0 * 64 + fo];
        g1[r] = *(const uint4*)&fsu[(size_t)s1 * 64 + fo];
    }

    half2v val[4];
    #pragma unroll
    for (int i = 0; i < 4; ++i) val[i] = (half2v){(_Float16)0.f, (_Float16)0.f};

    // ---- consume per relation (acc reused) ----
    #pragma unroll
    for (int r = 0; r < 4; ++r) {
        const int mr = m[r];
        if (mr == 0) continue;                       // wave-uniform branch
        const int rd = r * n + node;
        const unsigned* fsu = fs_all + (size_t)r * n * 64;

        half2v fdv[4] = {u2h(ufd[r].x), u2h(ufd[r].y), u2h(ufd[r].z), u2h(ufd[r].w)};
        half2v atv[4] = {u2h(uat[r].x), u2h(uat[r].y), u2h(uat[r].z), u2h(uat[r].w)};

        float den = 0.f;
        half2v acc[4];
        #pragma unroll
        for (int i = 0; i < 4; ++i) acc[i] = (half2v){(_Float16)0.f, (_Float16)0.f};

        edge4(g0[r], quarter < mr, fdv, atv, den, acc);
        if (mr > 4) edge4(g1[r], 4 + quarter < mr, fdv, atv, den, acc);

        if (mr > 8) {                                // P ~ 2%
            for (int p = 8; p < mr; p += 4) {
                const int ei = p + quarter;
                const bool ok = ei < mr;
                const int eic = ei < 31 ? ei : 31;
                int s = (eic < 15) ? rec[(size_t)rd * 16 + 1 + eic]
                                   : ovf[(size_t)(eic - 15) * L + rd];
                s = ok ? s : 0;
                const uint4 g = *(const uint4*)&fsu[(size_t)s * 64 + fo];
                edge4(g, ok, fdv, atv, den, acc);
            }
        }

        den += __shfl_xor(den, 16);
        den += __shfl_xor(den, 32);
        const half2v ih = pk2h(__builtin_amdgcn_rcpf(den));   // den > 0
        #pragma unroll
        for (int i = 0; i < 4; ++i) val[i] += acc[i] * ih;
    }

    // combine quarters' numerator contributions (packed)
    #pragma unroll
    for (int i = 0; i < 4; ++i) {
        val[i] = shfladd_h(val[i], 16);
        val[i] = shfladd_h(val[i], 32);
    }

    if (out_f32) {
        // mean over heads: lane q holds feats 8q..8q+7, head = q>>2
        #pragma unroll
        for (int i = 0; i < 4; ++i) {
            val[i] = shfladd_h(val[i], 4);
            val[i] = shfladd_h(val[i], 8);
        }
        if (lane < 4) {
            float* o = &out_f32[(size_t)node * 32 + 8 * lane];
            *(float4*)&o[0] = make_float4(0.25f * (float)val[0].x, 0.25f * (float)val[0].y,
                                          0.25f * (float)val[1].x, 0.25f * (float)val[1].y);
            *(float4*)&o[4] = make_float4(0.25f * (float)val[2].x, 0.25f * (float)val[2].y,
                                          0.25f * (float)val[3].x, 0.25f * (float)val[3].y);
        }
    } else {
        if (lane < 16) {
            uint4 o;
            o.x = h2u(val[0]); o.y = h2u(val[1]);
            o.z = h2u(val[2]); o.w = h2u(val[3]);
            *(uint4*)&out_h[(size_t)node * 64 + fo] = o;
        }
    }
}

// =====================================================================
extern "C" void kernel_launch(void* const* d_in, const int* in_sizes, int n_in,
                              void* d_out, int out_size, void* d_ws, size_t ws_size,
                              hipStream_t stream)
{
    const int n  = in_sizes[0] / FF;     // 50000
    const int R  = 4;
    const int ne = in_sizes[1] / R;      // 200000
    const int totalE = R * ne;
    const int L  = R * n;
    const int nrb = (n + 15) / 16;

    const float* x    = (const float*)d_in[0];
    const int*   esrc = (const int*)d_in[1];
    const int*   edst = (const int*)d_in[2];

    // ---- workspace layout ----
    char* p = (char*)d_ws;
    auto carve = [&p](size_t bytes) { char* q = p; p += (bytes + 255) & ~(size_t)255; return q; };
    unsigned*       hbA    = (unsigned*)      carve((size_t)n * 64 * 4);
    unsigned*       hbB    = (unsigned*)      carve((size_t)n * 64 * 4);
    unsigned short* fs_all = (unsigned short*)carve((size_t)R * n * FF * 2);
    unsigned short* fd_all = (unsigned short*)carve((size_t)R * n * FF * 2);
    unsigned short* Wp     = (unsigned short*)carve((size_t)3 * R * 2 * FF * FF * 2);
    unsigned*       attH   = (unsigned*)      carve((size_t)3 * R * 64 * 4);
    int*            rec    = (int*)           carve((size_t)L * 16 * 4);   // 64B records
    int*            ovf    = (int*)           carve((size_t)17 * L * 4);   // idx 15..31

    (void)hipMemsetAsync(rec, 0, (size_t)L * 16 * sizeof(int), stream);

    // ---- pack W0 + att ----
    pack0<<<515, 256, 0, stream>>>(
        (const float*)d_in[3], (const float*)d_in[5], Wp,
        (const float*)d_in[7], (const float*)d_in[12], (const float*)d_in[17],
        attH);

    // ---- fused: csr fill + gemm0 + pack W1/W2 ----
    const int CB = (totalE + 1023) / 1024;
    fused2<<<CB + G0F + 1024, 256, 0, stream>>>(
        esrc, edst, rec, ovf, totalE, ne, n, CB,
        x, Wp,
        (const float*)d_in[4], (const float*)d_in[6],
        fs_all, fd_all, nrb,
        (const float*)d_in[8],  (const float*)d_in[10],
        (const float*)d_in[13], (const float*)d_in[15],
        Wp);

    // ---- layers ----
    unsigned* bufs[3] = {hbA, hbB, nullptr};
    for (int l = 0; l < 3; ++l) {
        if (l > 0) {
            const float* bsrc = (const float*)d_in[3 + 5 * l + 1];
            const float* bdst = (const float*)d_in[3 + 5 * l + 3];
            mfma_gemm<<<GG, 256, 0, stream>>>(
                (const unsigned short*)bufs[l - 1],
                Wp + (size_t)l * R * 2 * FF * FF,
                bsrc, bdst, fs_all, fd_all, nrb, n);
        }
        const int last = (l == 2);
        aggregate<<<(n + 3) / 4, 256, 0, stream>>>(
            rec, ovf,
            (const unsigned*)fs_all, (const unsigned*)fd_all,
            attH + (size_t)l * R * 64,
            last ? nullptr : bufs[l],
            last ? (float*)d_out : nullptr, n);
    }
}

// Round 8
// 377.865 us; speedup vs baseline: 1.0859x; 1.0859x over previous
//
#include <hip/hip_runtime.h>
#include <math.h>

#define FF 128     // feature width (all layers)
#define G0F 1024   // gemm0 blocks inside fused3 (4/CU tail)
#define GG 2048    // mfma_gemm grid
// CSR binning: buckets of 256 rd; 8 writer-partitions (~XCD via blockIdx&7);
// per (part,bucket) capacity 256 (mean 128, +11 sd). Packing rdLocal<<16|src
// requires n < 65536 (problem: n = 50000).
#define BSH 8
#define CAPB 256

typedef _Float16 half2v __attribute__((ext_vector_type(2)));
typedef _Float16 f16x8  __attribute__((ext_vector_type(8)));
typedef __fp16   fp16x2 __attribute__((ext_vector_type(2)));
typedef __attribute__((ext_vector_type(4))) float f4v;

__device__ __forceinline__ half2v u2h(unsigned u) {
    union { unsigned u; half2v h; } c; c.u = u; return c.h;
}
__device__ __forceinline__ unsigned h2u(half2v h) {
    union { unsigned u; half2v h; } c; c.h = h; return c.u;
}
__device__ __forceinline__ unsigned short f2h(float f) {
    _Float16 h = (_Float16)f;
    unsigned short u; __builtin_memcpy(&u, &h, 2); return u;
}
__device__ __forceinline__ half2v pk2h(float e) {
    union { fp16x2 p; half2v h; } c;
    c.p = __builtin_amdgcn_cvt_pkrtz(e, e);
    return c.h;
}
__device__ __forceinline__ float dot2(half2v a, half2v b, float c) {
#if __has_builtin(__builtin_amdgcn_fdot2)
    union { half2v h; fp16x2 p; } ca, cb;
    ca.h = a; cb.h = b;
    return __builtin_amdgcn_fdot2(ca.p, cb.p, c, false);
#else
    return c + (float)a.x * (float)b.x + (float)a.y * (float)b.y;
#endif
}
__device__ __forceinline__ half2v shfladd_h(half2v v, int mask) {
    return v + u2h(__shfl_xor(h2u(v), mask));
}
// 16B-chunk XOR swizzle inside a [16 rows][256B] LDS tile.
__device__ __forceinline__ int swz16(int row, int chunk) {
    return row * 256 + (((chunk ^ row) & 15) << 4);
}

// =====================================================================
// R21. (a) aggregate REVERTED to R19 pair structure (R20's all-4 issue
// crossed a VGPR occupancy step: total 374->410, fused2 unchanged =>
// regression was aggregate-side). (b) CSR fill replaced by two-phase
// XCD-local binning: R17-R19 showed the scattered fill writes ~53MB for
// 3.2MB payload across THREE layouts -- cross-XCD temporal line sharing
// is the invariant cause. P2 (in fused3, overlapped with gemm0):
// append packed edges into (blockIdx&7, rd>>8) regions -- writers of a
// line share an XCD and are temporally clustered -> dense local
// writeback (~7MB). P3: per-bucket LDS record build (stride-17 banks),
// dense coalesced rec write; rec memset deleted.
// =====================================================================

// ---------------- pack0: pack W0 + att (tiny pre-kernel) -------------
__global__ __launch_bounds__(256) void pack0(
    const float* __restrict__ W0s_, const float* __restrict__ W0d_,
    unsigned short* __restrict__ Wp,
    const float* __restrict__ a0, const float* __restrict__ a1,
    const float* __restrict__ a2, unsigned* __restrict__ attH)
{
    int b = blockIdx.x;
    const int tid = threadIdx.x;
    if (b < 512) {                       // 4r x 2mat x 128 x 128 = 131072
        const int t = b * 256 + tid;
        const int r   = t >> 15;
        const int mat = (t >> 14) & 1;
        const int idx = t & 16383;
        const int k = idx >> 7, nn = idx & 127;
        const float* W = mat ? W0d_ : W0s_;
        const float v = W[((size_t)r * FF + k) * FF + nn];
        const int nb = nn >> 4, lo = nn & 15;
        const int ks = k >> 5, quad = (k >> 3) & 3, j = k & 7;
        const int lane = quad * 16 + lo;
        const size_t o = ((((((size_t)r * 2 + mat) * 8 + nb) * 4 + ks) * 64 + lane) * 8) + j;
        Wp[o] = f2h(v);
        return;
    }
    b -= 512;
    const int t = b * 256 + tid;
    if (t >= 768) return;
    const int l = t >> 8, rest = t & 255;
    const float* a = (l == 0) ? a0 : (l == 1) ? a1 : a2;
    const float2 v = ((const float2*)a)[rest];
    half2v h = {(_Float16)v.x, (_Float16)v.y};
    attH[t] = h2u(h);
}

// ------- fused3: P2 edge-binning + gemm0 + pack W1/W2 ----------------
//   blocks [0, CB2)             : P2 scatter (4 edges/thread)
//   blocks [CB2, CB2+G0F)       : layer-0 GEMM from packed Wp
//   blocks [CB2+G0F, +1024)     : pack W1, W2
__global__ __launch_bounds__(256, 4) void fused3(
    const int* __restrict__ esrc_all, const int* __restrict__ edst_all,
    int* __restrict__ bcur, unsigned* __restrict__ bbuf,
    int totalE, int ne, int n, int NB, int CB2,
    const float* __restrict__ x,
    const unsigned short* __restrict__ Wp,
    const float* __restrict__ bs0, const float* __restrict__ bd0,
    unsigned short* __restrict__ fs_all, unsigned short* __restrict__ fd_all,
    int nrb,
    const float* __restrict__ W1s_, const float* __restrict__ W1d_,
    const float* __restrict__ W2s_, const float* __restrict__ W2d_,
    unsigned short* __restrict__ Wp_full)
{
    __shared__ char lsA[4096];
    __shared__ char lsC[8192];

    int b = blockIdx.x;
    const int tid = threadIdx.x;

    if (b < CB2) {
        // ---- P2: scatter edges into (part, bucket) append regions ----
        const int part = b & 7;          // ~XCD under round-robin dispatch
        const int t0 = b * 1024 + tid;
        #pragma unroll
        for (int k = 0; k < 4; ++k) {
            const int i = t0 + k * 256;
            if (i < totalE) {
                const int r = i / ne;
                const int rd = r * n + edst_all[i];
                const int src = esrc_all[i];
                const int bkt = rd >> BSH;
                const int reg = part * NB + bkt;
                const int pos = atomicAdd(&bcur[reg << 4], 1);   // line-padded
                if (pos < CAPB)
                    bbuf[((size_t)reg << 8) + pos] =
                        ((unsigned)(rd & 255) << 16) | (unsigned)src;
            }
        }
        return;
    }
    b -= CB2;

    if (b < G0F) {
        // ---- layer-0 GEMM (f32 x, packed-Wp B), LDS-staged ----
        const int wave = tid >> 6, lane = tid & 63;
        const int r = b & 3;
        const int half = wave & 1;
        const int mat  = wave >> 1;
        const int lo = lane & 15, quad = lane >> 4;

        const unsigned short* Wr = Wp + (size_t)r * 2 * FF * FF;
        const float* bp = mat ? bd0 : bs0;
        unsigned short* fs = fs_all + (size_t)r * n * FF;
        unsigned short* fd = fd_all + (size_t)r * n * FF;

        f16x8 B[4][4];
        #pragma unroll
        for (int nbi = 0; nbi < 4; ++nbi)
            #pragma unroll
            for (int ks = 0; ks < 4; ++ks) {
                const int nb = half * 4 + nbi;
                B[nbi][ks] = *(const f16x8*)
                    &Wr[(((((size_t)mat * 8 + nb) * 4 + ks) * 64 + lane) * 8)];
            }

        float bias[4];
        #pragma unroll
        for (int nbi = 0; nbi < 4; ++nbi)
            bias[nbi] = bp[r * FF + (half * 4 + nbi) * 16 + lo];

        const int srow = tid >> 4, schunk = tid & 15;
        const int stride = G0F >> 2;
        for (int rb = b >> 2; rb < nrb; rb += stride) {
            const int row0 = rb * 16;
            {
                const float* xs = &x[(size_t)row0 * FF + tid * 8];
                const float4 p0 = *(const float4*)&xs[0];
                const float4 p1 = *(const float4*)&xs[4];
                f16x8 v;
                v[0] = (_Float16)p0.x; v[1] = (_Float16)p0.y;
                v[2] = (_Float16)p0.z; v[3] = (_Float16)p0.w;
                v[4] = (_Float16)p1.x; v[5] = (_Float16)p1.y;
                v[6] = (_Float16)p1.z; v[7] = (_Float16)p1.w;
                *(f16x8*)&lsA[swz16(srow, schunk)] = v;
            }
            __syncthreads();

            f16x8 A[4];
            #pragma unroll
            for (int ks = 0; ks < 4; ++ks)
                A[ks] = *(const f16x8*)&lsA[swz16(lo, ks * 4 + quad)];

            f4v c[4];
            #pragma unroll
            for (int nbi = 0; nbi < 4; ++nbi)
                c[nbi] = (f4v){bias[nbi], bias[nbi], bias[nbi], bias[nbi]};

            #pragma unroll
            for (int ks = 0; ks < 4; ++ks)
                #pragma unroll
                for (int nbi = 0; nbi < 4; ++nbi)
                    c[nbi] = __builtin_amdgcn_mfma_f32_16x16x32_f16(
                        A[ks], B[nbi][ks], c[nbi], 0, 0, 0);

            #pragma unroll
            for (int nbi = 0; nbi < 4; ++nbi)
                #pragma unroll
                for (int i = 0; i < 4; ++i) {
                    const int row = quad * 4 + i;
                    const int cb  = ((half * 4 + nbi) * 16 + lo) * 2;
                    *(unsigned short*)&lsC[mat * 4096 + swz16(row, cb >> 4) + (cb & 15)]
                        = f2h(c[nbi][i]);
                }
            __syncthreads();

            #pragma unroll
            for (int p = 0; p < 2; ++p) {
                const int unit = p * 256 + tid;
                const int m    = unit >> 8;
                const int row  = (unit >> 4) & 15;
                const int ch   = unit & 15;
                const uint4 d = *(const uint4*)&lsC[m * 4096 + swz16(row, ch)];
                unsigned short* out = m ? fd : fs;
                *(uint4*)&out[(size_t)(row0 + row) * FF + ch * 8] = d;
            }
            __syncthreads();
        }
        return;
    }
    b -= G0F;

    // ---- pack W for layers 1,2 ----
    const int t = b * 256 + tid;
    if (t >= 2 * 4 * 2 * FF * FF) return;
    const int l    = 1 + (t >> 17);
    const int rest = t & 131071;
    const int r    = rest >> 15;
    const int mat  = (rest >> 14) & 1;
    const int idx  = rest & 16383;
    const int k = idx >> 7, nn = idx & 127;
    const float* W = (l == 1) ? (mat ? W1d_ : W1s_)
                              : (mat ? W2d_ : W2s_);
    const float v = W[((size_t)r * FF + k) * FF + nn];
    const int nb = nn >> 4, lo = nn & 15;
    const int ks = k >> 5, quad = (k >> 3) & 3, j = k & 7;
    const int lane = quad * 16 + lo;
    const size_t o = (((((((size_t)l * 4 + r) * 2 + mat) * 8 + nb) * 4 + ks) * 64 + lane) * 8) + j;
    Wp_full[o] = f2h(v);
}

// ------- p3build: per-bucket LDS record build -> dense rec -----------
__global__ __launch_bounds__(256) void p3build(
    const int* __restrict__ bcur, const unsigned* __restrict__ bbuf,
    int* __restrict__ rec, int* __restrict__ ovf, int NB, int L)
{
    __shared__ int lrec[256 * 17];       // stride 17: spreads LDS-atomic banks
    const int b = blockIdx.x;
    const int tid = threadIdx.x;

    #pragma unroll
    for (int k = 0; k < 17; ++k) lrec[k * 256 + tid] = 0;
    __syncthreads();

    const int rd0 = b << BSH;
    for (int part = 0; part < 8; ++part) {
        const int reg = part * NB + b;
        int c = bcur[reg << 4];
        c = c < CAPB ? c : CAPB;
        const unsigned* seg = &bbuf[(size_t)reg << 8];
        for (int e = tid; e < c; e += 256) {
            const unsigned v = seg[e];
            const int rdL = v >> 16;
            const int src = (int)(v & 0xFFFFu);
            const int idx = atomicAdd(&lrec[rdL * 17], 1);
            if (idx < 15)      lrec[rdL * 17 + 1 + idx] = src;
            else if (idx < 32) ovf[(size_t)(idx - 15) * L + rd0 + rdL] = src;
        }
    }
    __syncthreads();

    if (rd0 + tid < L) {
        int* out = &rec[(size_t)(rd0 + tid) * 16];
        #pragma unroll
        for (int w = 0; w < 4; ++w) {
            int4 d;
            d.x = lrec[tid * 17 + w * 4 + 0];
            d.y = lrec[tid * 17 + w * 4 + 1];
            d.z = lrec[tid * 17 + w * 4 + 2];
            d.w = lrec[tid * 17 + w * 4 + 3];
            *(int4*)&out[w * 4] = d;
        }
    }
}

// =====================================================================
// Batched MFMA GEMM over all 4 relations, f16 inputs (layers 1,2).
// =====================================================================
__global__ __launch_bounds__(256, 4) void mfma_gemm(
    const unsigned short* __restrict__ hb,
    const unsigned short* __restrict__ Wp,
    const float* __restrict__ bs_all,
    const float* __restrict__ bd_all,
    unsigned short* __restrict__ fs_all,
    unsigned short* __restrict__ fd_all,
    int nrb, int n)
{
    __shared__ char lsA[4096];
    __shared__ char lsC[8192];

    const int tid = threadIdx.x;
    const int wave = tid >> 6, lane = tid & 63;
    const int r = blockIdx.x & 3;
    const int half = wave & 1;
    const int mat  = wave >> 1;
    const int lo = lane & 15, quad = lane >> 4;

    const unsigned short* Wr = Wp + (size_t)r * 2 * FF * FF;
    const float* bp = mat ? bd_all : bs_all;
    unsigned short* fs = fs_all + (size_t)r * n * FF;
    unsigned short* fd = fd_all + (size_t)r * n * FF;

    f16x8 B[4][4];
    #pragma unroll
    for (int nbi = 0; nbi < 4; ++nbi)
        #pragma unroll
        for (int ks = 0; ks < 4; ++ks) {
            const int nb = half * 4 + nbi;
            B[nbi][ks] = *(const f16x8*)
                &Wr[(((((size_t)mat * 8 + nb) * 4 + ks) * 64 + lane) * 8)];
        }

    float bias[4];
    #pragma unroll
    for (int nbi = 0; nbi < 4; ++nbi)
        bias[nbi] = bp[r * FF + (half * 4 + nbi) * 16 + lo];

    const int srow = tid >> 4, schunk = tid & 15;
    const int stride = gridDim.x >> 2;
    for (int rb = blockIdx.x >> 2; rb < nrb; rb += stride) {
        const int row0 = rb * 16;
        {
            const uint4 g = *(const uint4*)&hb[(size_t)row0 * FF + tid * 8];
            *(uint4*)&lsA[swz16(srow, schunk)] = g;
        }
        __syncthreads();

        f16x8 A[4];
        #pragma unroll
        for (int ks = 0; ks < 4; ++ks)
            A[ks] = *(const f16x8*)&lsA[swz16(lo, ks * 4 + quad)];

        f4v c[4];
        #pragma unroll
        for (int nbi = 0; nbi < 4; ++nbi)
            c[nbi] = (f4v){bias[nbi], bias[nbi], bias[nbi], bias[nbi]};

        #pragma unroll
        for (int ks = 0; ks < 4; ++ks)
            #pragma unroll
            for (int nbi = 0; nbi < 4; ++nbi)
                c[nbi] = __builtin_amdgcn_mfma_f32_16x16x32_f16(
                    A[ks], B[nbi][ks], c[nbi], 0, 0, 0);

        #pragma unroll
        for (int nbi = 0; nbi < 4; ++nbi)
            #pragma unroll
            for (int i = 0; i < 4; ++i) {
                const int row = quad * 4 + i;
                const int cb  = ((half * 4 + nbi) * 16 + lo) * 2;
                *(unsigned short*)&lsC[mat * 4096 + swz16(row, cb >> 4) + (cb & 15)]
                    = f2h(c[nbi][i]);
            }
        __syncthreads();

        #pragma unroll
        for (int p = 0; p < 2; ++p) {
            const int unit = p * 256 + tid;
            const int m    = unit >> 8;
            const int row  = (unit >> 4) & 15;
            const int ch   = unit & 15;
            const uint4 d = *(const uint4*)&lsC[m * 4096 + swz16(row, ch)];
            unsigned short* out = m ? fd : fs;
            *(uint4*)&out[(size_t)(row0 + row) * FF + ch * 8] = d;
        }
        __syncthreads();
    }
}

// =====================================================================
// Fused aggregate -- R19 pair structure (reverted from R20).
// =====================================================================
__device__ __forceinline__ void edge4(
    uint4 g, bool ok, const half2v* fdv, const half2v* atv,
    float& den, half2v* acc)
{
    const half2v C02 = {(_Float16)0.2f, (_Float16)0.2f};
    half2v f[4] = {u2h(g.x), u2h(g.y), u2h(g.z), u2h(g.w)};
    float v = 0.f;
    #pragma unroll
    for (int i = 0; i < 4; ++i) {
        const half2v z = f[i] + fdv[i];
        const half2v l = __builtin_elementwise_max(z, z * C02);
        v = dot2(l, atv[i], v);
    }
    v += __shfl_xor(v, 2);
    v += __shfl_xor(v, 1);
    const float e = ok ? __expf(v) : 0.f;
    den += e;
    const half2v eh = pk2h(e);
    #pragma unroll
    for (int i = 0; i < 4; ++i) acc[i] += eh * f[i];
}

__global__ __launch_bounds__(256) void aggregate(
    const int* __restrict__ rec,             // [R*n][16] {cnt, s0..s14}
    const int* __restrict__ ovf,             // [17][R*n] planes, idx 15..31
    const unsigned* __restrict__ fs_all,     // [R][n][64] f16 pairs
    const unsigned* __restrict__ fd_all,
    const unsigned* __restrict__ att_h,      // this layer: [R][64] f16 pairs
    unsigned* __restrict__ out_h,            // [n][64] or null
    float* __restrict__ out_f32,             // [n][32] or null
    int n)
{
    const int node = blockIdx.x * 4 + (threadIdx.x >> 6);
    if (node >= n) return;
    const int lane = threadIdx.x & 63;
    const int quarter = lane >> 4;
    const int q = lane & 15;
    const int fo = 4 * q;
    const int L = n << 2;

    int m[4], i0[4], i1[4];
    #pragma unroll
    for (int r = 0; r < 4; ++r) {
        const int rd = r * n + node;
        const int* rp = &rec[(size_t)rd * 16];
        m[r]  = rp[0];
        i0[r] = rp[1 + quarter];
        i1[r] = rp[5 + quarter];
    }

    half2v val[4];
    #pragma unroll
    for (int i = 0; i < 4; ++i) val[i] = (half2v){(_Float16)0.f, (_Float16)0.f};

    #pragma unroll
    for (int rp2 = 0; rp2 < 2; ++rp2) {
        const int ra = 2 * rp2, rb = 2 * rp2 + 1;
        const int rdA = ra * n + node;
        const int rdB = rb * n + node;
        const int mA = m[ra], mB = m[rb];
        const unsigned* fsuA = fs_all + (size_t)ra * n * 64;
        const unsigned* fsuB = fs_all + (size_t)rb * n * 64;

        const uint4 ufdA = *(const uint4*)&fd_all[(size_t)rdA * 64 + fo];
        const uint4 ufdB = *(const uint4*)&fd_all[(size_t)rdB * 64 + fo];
        const uint4 uatA = *(const uint4*)&att_h[ra * 64 + fo];
        const uint4 uatB = *(const uint4*)&att_h[rb * 64 + fo];

        const bool okA0 = quarter < mA, okA1 = 4 + quarter < mA;
        const bool okB0 = quarter < mB, okB1 = 4 + quarter < mB;
        int iA0 = okA0 ? i0[ra] : 0;
        int iB0 = okB0 ? i0[rb] : 0;
        int iA1 = okA1 ? i1[ra] : 0;
        int iB1 = okB1 ? i1[rb] : 0;
        const uint4 gA0 = *(const uint4*)&fsuA[(size_t)iA0 * 64 + fo];
        const uint4 gB0 = *(const uint4*)&fsuB[(size_t)iB0 * 64 + fo];
        const uint4 gA1 = *(const uint4*)&fsuA[(size_t)iA1 * 64 + fo];
        const uint4 gB1 = *(const uint4*)&fsuB[(size_t)iB1 * 64 + fo];

        half2v fdvA[4] = {u2h(ufdA.x), u2h(ufdA.y), u2h(ufdA.z), u2h(ufdA.w)};
        half2v atvA[4] = {u2h(uatA.x), u2h(uatA.y), u2h(uatA.z), u2h(uatA.w)};
        half2v fdvB[4] = {u2h(ufdB.x), u2h(ufdB.y), u2h(ufdB.z), u2h(ufdB.w)};
        half2v atvB[4] = {u2h(uatB.x), u2h(uatB.y), u2h(uatB.z), u2h(uatB.w)};

        float denA = 0.f, denB = 0.f;
        half2v accA[4], accB[4];
        #pragma unroll
        for (int i = 0; i < 4; ++i) {
            accA[i] = (half2v){(_Float16)0.f, (_Float16)0.f};
            accB[i] = (half2v){(_Float16)0.f, (_Float16)0.f};
        }

        edge4(gA0, okA0, fdvA, atvA, denA, accA);
        edge4(gB0, okB0, fdvB, atvB, denB, accB);
        if (mA > 4) edge4(gA1, okA1, fdvA, atvA, denA, accA);
        if (mB > 4) edge4(gB1, okB1, fdvB, atvB, denB, accB);

        if (mA > 8) {                        // P ~ 2%
            for (int p = 8; p < mA; p += 4) {
                const int ei = p + quarter;
                const bool ok = ei < mA;
                const int eic = ei < 31 ? ei : 31;
                int s = (eic < 15) ? rec[(size_t)rdA * 16 + 1 + eic]
                                   : ovf[(size_t)(eic - 15) * L + rdA];
                s = ok ? s : 0;
                const uint4 g = *(const uint4*)&fsuA[(size_t)s * 64 + fo];
                edge4(g, ok, fdvA, atvA, denA, accA);
            }
        }
        if (mB > 8) {
            for (int p = 8; p < mB; p += 4) {
                const int ei = p + quarter;
                const bool ok = ei < mB;
                const int eic = ei < 31 ? ei : 31;
                int s = (eic < 15) ? rec[(size_t)rdB * 16 + 1 + eic]
                                   : ovf[(size_t)(eic - 15) * L + rdB];
                s = ok ? s : 0;
                const uint4 g = *(const uint4*)&fsuB[(size_t)s * 64 + fo];
                edge4(g, ok, fdvB, atvB, denB, accB);
            }
        }

        if (mA) {
            denA += __shfl_xor(denA, 16);
            denA += __shfl_xor(denA, 32);
            const half2v ih = pk2h(__builtin_amdgcn_rcpf(denA));   // denA > 0
            #pragma unroll
            for (int i = 0; i < 4; ++i) val[i] += accA[i] * ih;
        }
        if (mB) {
            denB += __shfl_xor(denB, 16);
            denB += __shfl_xor(denB, 32);
            const half2v ih = pk2h(__builtin_amdgcn_rcpf(denB));   // denB > 0
            #pragma unroll
            for (int i = 0; i < 4; ++i) val[i] += accB[i] * ih;
        }
    }

    // combine quarters' numerator contributions (packed)
    #pragma unroll
    for (int i = 0; i < 4; ++i) {
        val[i] = shfladd_h(val[i], 16);
        val[i] = shfladd_h(val[i], 32);
    }

    if (out_f32) {
        // mean over heads: lane q holds feats 8q..8q+7, head = q>>2
        #pragma unroll
        for (int i = 0; i < 4; ++i) {
            val[i] = shfladd_h(val[i], 4);
            val[i] = shfladd_h(val[i], 8);
        }
        if (lane < 4) {
            float* o = &out_f32[(size_t)node * 32 + 8 * lane];
            *(float4*)&o[0] = make_float4(0.25f * (float)val[0].x, 0.25f * (float)val[0].y,
                                          0.25f * (float)val[1].x, 0.25f * (float)val[1].y);
            *(float4*)&o[4] = make_float4(0.25f * (float)val[2].x, 0.25f * (float)val[2].y,
                                          0.25f * (float)val[3].x, 0.25f * (float)val[3].y);
        }
    } else {
        if (lane < 16) {
            uint4 o;
            o.x = h2u(val[0]); o.y = h2u(val[1]);
            o.z = h2u(val[2]); o.w = h2u(val[3]);
            *(uint4*)&out_h[(size_t)node * 64 + fo] = o;
        }
    }
}

// =====================================================================
extern "C" void kernel_launch(void* const* d_in, const int* in_sizes, int n_in,
                              void* d_out, int out_size, void* d_ws, size_t ws_size,
                              hipStream_t stream)
{
    const int n  = in_sizes[0] / FF;     // 50000
    const int R  = 4;
    const int ne = in_sizes[1] / R;      // 200000
    const int totalE = R * ne;
    const int L  = R * n;
    const int nrb = (n + 15) / 16;
    const int NB = (L + 255) >> BSH;     // 782 buckets of 256 rd

    const float* x    = (const float*)d_in[0];
    const int*   esrc = (const int*)d_in[1];
    const int*   edst = (const int*)d_in[2];

    // ---- workspace layout ----
    char* p = (char*)d_ws;
    auto carve = [&p](size_t bytes) { char* q = p; p += (bytes + 255) & ~(size_t)255; return q; };
    unsigned*       hbA    = (unsigned*)      carve((size_t)n * 64 * 4);
    unsigned*       hbB    = (unsigned*)      carve((size_t)n * 64 * 4);
    unsigned short* fs_all = (unsigned short*)carve((size_t)R * n * FF * 2);
    unsigned short* fd_all = (unsigned short*)carve((size_t)R * n * FF * 2);
    unsigned short* Wp     = (unsigned short*)carve((size_t)3 * R * 2 * FF * FF * 2);
    unsigned*       attH   = (unsigned*)      carve((size_t)3 * R * 64 * 4);
    int*            rec    = (int*)           carve((size_t)L * 16 * 4);        // 64B records
    int*            ovf    = (int*)           carve((size_t)17 * L * 4);        // idx 15..31
    int*            bcur   = (int*)           carve((size_t)8 * NB * 16 * 4);   // line-padded counters
    unsigned*       bbuf   = (unsigned*)      carve((size_t)8 * NB * CAPB * 4); // packed edges

    (void)hipMemsetAsync(bcur, 0, (size_t)8 * NB * 16 * sizeof(int), stream);

    // ---- pack W0 + att ----
    pack0<<<515, 256, 0, stream>>>(
        (const float*)d_in[3], (const float*)d_in[5], Wp,
        (const float*)d_in[7], (const float*)d_in[12], (const float*)d_in[17],
        attH);

    // ---- fused: P2 binning + gemm0 + pack W1/W2 ----
    const int CB2 = (totalE + 1023) / 1024;
    fused3<<<CB2 + G0F + 1024, 256, 0, stream>>>(
        esrc, edst, bcur, bbuf, totalE, ne, n, NB, CB2,
        x, Wp,
        (const float*)d_in[4], (const float*)d_in[6],
        fs_all, fd_all, nrb,
        (const float*)d_in[8],  (const float*)d_in[10],
        (const float*)d_in[13], (const float*)d_in[15],
        Wp);

    // ---- P3: build records (also replaces rec memset) ----
    p3build<<<NB, 256, 0, stream>>>(bcur, bbuf, rec, ovf, NB, L);

    // ---- layers ----
    unsigned* bufs[3] = {hbA, hbB, nullptr};
    for (int l = 0; l < 3; ++l) {
        if (l > 0) {
            const float* bsrc = (const float*)d_in[3 + 5 * l + 1];
            const float* bdst = (const float*)d_in[3 + 5 * l + 3];
            mfma_gemm<<<GG, 256, 0, stream>>>(
                (const unsigned short*)bufs[l - 1],
                Wp + (size_t)l * R * 2 * FF * FF,
                bsrc, bdst, fs_all, fd_all, nrb, n);
        }
        const int last = (l == 2);
        aggregate<<<(n + 3) / 4, 256, 0, stream>>>(
            rec, ovf,
            (const unsigned*)fs_all, (const unsigned*)fd_all,
            attH + (size_t)l * R * 64,
            last ? nullptr : bufs[l],
            last ? (float*)d_out : nullptr, n);
    }
}